// Round 5
// baseline (278.293 us; speedup 1.0000x reference)
//
#include <hip/hip_runtime.h>

// EdgeLoss: mean(|sobel_x(sr)-sobel_x(hr)| + |sobel_y(sr)-sobel_y(hr)|)
// = mean(|sobel_x(d)| + |sobel_y(d)|), d = sr - hr (conv linearity; the
// 180-deg kernel flip only flips sign, erased by abs).
// Separable: s = [1,2,1]*d (horiz), t = [1,0,-1]*d (horiz);
//            gx = [1,2,1]^T * t (vert), gy = [1,0,-1]^T * s (vert).
//
// R5: global_load_lds DMA staging. R2-R4 post-mortems proved the compiler
// always sinks register-batch loads to MLP~1 (VGPR stuck at 64, 1.7 TB/s,
// latency-bound). global_load_lds has NO destination VGPRs -> nothing to
// sink; 20 x 1KB async loads queue per wave, one vmcnt drain per block.
// LDS = exactly 80 KB -> 2 resident blocks/CU -> 160 KB in flight/CU.

#define IMG_H 1024
#define IMG_W 1024
#define IMG_B 32
#define CH 8                    // output rows per block
#define NROW (CH + 2)           // staged rows (vertical halo)
#define NCHUNK (IMG_H / CH)     // 128 -> grid 4096 blocks

typedef __attribute__((address_space(1))) const void GCV;
typedef __attribute__((address_space(3))) void LDSV;

// Build s/t (horizontal smooth/diff) for one staged row from LDS.
// m zeroes logically-out-of-image rows. Halo via intra-wave shuffle;
// lanes 0/63 read the neighbor column straight from LDS (full row staged).
__device__ __forceinline__ void row_st_lds(const float* __restrict__ A,
                                           const float* __restrict__ Bb,
                                           int x0, float m, int lane,
                                           float4& s, float4& t) {
    const float4 a  = *reinterpret_cast<const float4*>(A + x0);
    const float4 bb = *reinterpret_cast<const float4*>(Bb + x0);
    float4 d;
    d.x = (a.x - bb.x) * m;
    d.y = (a.y - bb.y) * m;
    d.z = (a.z - bb.z) * m;
    d.w = (a.w - bb.w) * m;
    float dl = __shfl_up(d.w, 1, 64);
    float dr = __shfl_down(d.x, 1, 64);
    if (lane == 0)  dl = (x0 > 0)           ? (A[x0 - 1] - Bb[x0 - 1]) * m : 0.f;
    if (lane == 63) dr = (x0 + 4 < IMG_W)   ? (A[x0 + 4] - Bb[x0 + 4]) * m : 0.f;
    s.x = dl  + 2.f * d.x + d.y;
    s.y = d.x + 2.f * d.y + d.z;
    s.z = d.y + 2.f * d.z + d.w;
    s.w = d.z + 2.f * d.w + dr;
    t.x = dl  - d.y;
    t.y = d.x - d.z;
    t.z = d.y - d.w;
    t.w = d.z - dr;
}

__global__ __launch_bounds__(256) void edge_loss_kernel(
        const float* __restrict__ sr, const float* __restrict__ hr,
        float* __restrict__ out, float invN) {
    // [inp][row][col] : 2 * 10 * 1024 floats = 81920 B exactly (2 blocks/CU).
    __shared__ float lds[2 * NROW * IMG_W];

    const int chunk = blockIdx.x;
    const int b     = blockIdx.y;
    const int tid   = threadIdx.x;
    const int wave  = tid >> 6;
    const int lane  = tid & 63;
    const size_t img = (size_t)b * IMG_H * IMG_W;
    const int y0 = chunk * CH;

    // ---- DMA stage: 80 x 1KB chunks; waves 0,1 -> sr, waves 2,3 -> hr ----
    {
        const int inp   = wave >> 1;                 // 0: sr, 1: hr
        const float* src = inp ? hr : sr;
        #pragma unroll
        for (int j = 0; j < 20; ++j) {
            const int rem = (wave & 1) * 20 + j;     // [0,40) within input
            const int r   = rem >> 2;                // staged row [0,10)
            const int q   = rem & 3;                 // quarter-row (256 floats)
            const int yc  = min(max(y0 - 1 + r, 0), IMG_H - 1);  // clamp; mask later
            const float* g = src + img + (size_t)yc * IMG_W + q * 256 + lane * 4;
            // wave-uniform LDS base; HW scatters lane i at base + i*16
            float* l = &lds[(inp * 40 + rem) * 256];
            __builtin_amdgcn_global_load_lds((GCV*)g, (LDSV*)l, 16, 0, 0);
        }
    }
    __syncthreads();   // compiler emits s_waitcnt vmcnt(0) before s_barrier

    // ---- compute: 3-row sliding s/t window over the staged slab ----
    const int x0 = tid * 4;
    const float* Ab = lds;                    // sr rows
    const float* Bb = lds + NROW * IMG_W;     // hr rows
    const float mtop = (y0 > 0) ? 1.f : 0.f;
    const float mbot = (y0 + CH < IMG_H) ? 1.f : 0.f;

    float4 s0, t0, s1, t1, s2, t2;
    row_st_lds(Ab,          Bb,          x0, mtop, lane, s0, t0);
    row_st_lds(Ab + IMG_W,  Bb + IMG_W,  x0, 1.f,  lane, s1, t1);

    float acc = 0.f;
    #pragma unroll
    for (int r = 2; r < NROW; ++r) {
        const float m = (r == NROW - 1) ? mbot : 1.f;
        row_st_lds(Ab + r * IMG_W, Bb + r * IMG_W, x0, m, lane, s2, t2);

        float gx, gy;
        gx = t0.x + 2.f * t1.x + t2.x;  gy = s0.x - s2.x;  acc += fabsf(gx) + fabsf(gy);
        gx = t0.y + 2.f * t1.y + t2.y;  gy = s0.y - s2.y;  acc += fabsf(gx) + fabsf(gy);
        gx = t0.z + 2.f * t1.z + t2.z;  gy = s0.z - s2.z;  acc += fabsf(gx) + fabsf(gy);
        gx = t0.w + 2.f * t1.w + t2.w;  gy = s0.w - s2.w;  acc += fabsf(gx) + fabsf(gy);

        s0 = s1; t0 = t1; s1 = s2; t1 = t2;
    }

    // ---- reduction: wave shuffle -> reuse staging LDS -> 1 atomic/block ----
    #pragma unroll
    for (int off = 32; off > 0; off >>= 1)
        acc += __shfl_down(acc, off, 64);

    __syncthreads();               // all staged-data reads done before overwrite
    if (lane == 0) lds[wave] = acc;
    __syncthreads();
    if (tid == 0)
        atomicAdd(out, (lds[0] + lds[1] + lds[2] + lds[3]) * invN);
}

extern "C" void kernel_launch(void* const* d_in, const int* in_sizes, int n_in,
                              void* d_out, int out_size, void* d_ws, size_t ws_size,
                              hipStream_t stream) {
    const float* sr = (const float*)d_in[0];
    const float* hr = (const float*)d_in[1];
    float* out = (float*)d_out;

    hipMemsetAsync(out, 0, sizeof(float), stream);

    dim3 grid(NCHUNK, IMG_B);
    const float invN = 1.0f / (float)((size_t)IMG_B * IMG_H * IMG_W);
    edge_loss_kernel<<<grid, 256, 0, stream>>>(sr, hr, out, invN);
}